// Round 9
// baseline (189.560 us; speedup 1.0000x reference)
//
#include <hip/hip_runtime.h>
#include <stdint.h>

// Problem constants (B, L, DIM) = (2, 2048, 1024); H=16, DH=64, W=256.
#define B_    2
#define L_    2048
#define DIM_  1024
#define H_    16
#define DH_   64
#define WWIN  256

typedef __attribute__((ext_vector_type(4))) float f32x4;
typedef __attribute__((ext_vector_type(8))) short bf16x8;

__device__ __forceinline__ unsigned short f2bf(float x) {
  union { float f; unsigned u; } c; c.f = x;
  unsigned r = c.u + 0x7fffu + ((c.u >> 16) & 1u);   // RNE
  return (unsigned short)(r >> 16);
}

// ---------------------------------------------------------------- cast fp32->bf16
// Flat exact grid: 3 activation arrays x 4096 blocks + 4 weight arrays x 1024.
struct CastArgs {
  const float* src[7];
  unsigned short* dst[7];
};
__global__ __launch_bounds__(256) void cast_bf16_kernel(CastArgs a) {
  int bid = blockIdx.x;
  int arr, base;
  if (bid < 12288) {            // activations: SA/1024 = 4096 blocks each
    arr = bid >> 12;
    base = (bid & 4095) << 10;
  } else {                      // weights: SW/1024 = 1024 blocks each
    int t = bid - 12288;
    arr = 3 + (t >> 10);
    base = (t & 1023) << 10;
  }
  int i = base + (int)threadIdx.x * 4;
  float4 v = *(const float4*)(a.src[arr] + i);
  ushort4 o;
  o.x = f2bf(v.x); o.y = f2bf(v.y); o.z = f2bf(v.z); o.w = f2bf(v.w);
  *(ushort4*)(a.dst[arr] + i) = o;
}

// ---------------------------------------------------------------- GEMM cores
#define BM 128
#define BN 64
#define BK 64

__device__ __forceinline__ void gld_lds16(const void* g, void* l) {
  __builtin_amdgcn_global_load_lds(
      (const __attribute__((address_space(1))) void*)g,
      (__attribute__((address_space(3))) void*)l, 16, 0, 0);
}

// R16: 128x128 tile, BK=32, 2x2 wave grid, acc[4][4]; single-barrier ping-pong
// in 32 KB LDS (2 x 8KB per operand) -> 3 blocks/CU at grid 768. Halves the
// per-FLOP LDS fragment traffic vs the 128x64 tile (8 frags / 16 MFMA per
// K-step) while keeping the proven ping-pong latency structure.
// As, Bs: 2 x 4096 shorts each.
__device__ __forceinline__ void gemm_core_128x128_bk32(
    const unsigned short* __restrict__ A, const unsigned short* __restrict__ Bt,
    unsigned short* As, unsigned short* Bs, f32x4 (&acc)[4][4],
    int m0, int n0) {
  const int tid = threadIdx.x;
  const int wave = tid >> 6, lane = tid & 63;
  const int quad = lane >> 4, l16 = lane & 15;
  const int wm = wave >> 1, wn = wave & 1;

  auto stage = [&](int k0, int buf) {
    unsigned short* Ad = As + buf * 4096;
    unsigned short* Bd = Bs + buf * 4096;
    #pragma unroll
    for (int rd = 0; rd < 2; ++rd) {       // A: 128 rows x 4 chunks (16B)
      int ci = rd * 256 + tid;
      int row = ci >> 2, ch = ci & 3;
      int gch = ch ^ (row & 3);            // pre-swizzled global chunk, linear LDS
      gld_lds16(A + (size_t)(m0 + row) * 1024 + k0 + gch * 8, Ad + ci * 8);
    }
    #pragma unroll
    for (int rd = 0; rd < 2; ++rd) {       // B: 128 rows x 4 chunks
      int ci = rd * 256 + tid;
      int row = ci >> 2, ch = ci & 3;
      int gch = ch ^ (row & 3);
      gld_lds16(Bt + (size_t)(n0 + row) * 1024 + k0 + gch * 8, Bd + ci * 8);
    }
  };

  stage(0, 0);
  for (int k = 0; k < 32; ++k) {
    const int cur = k & 1;
    __syncthreads();                       // buf[cur] staged; prev readers done
    if (k < 31) stage((k + 1) * 32, cur ^ 1);
    const unsigned short* Ac = As + cur * 4096;
    const unsigned short* Bc = Bs + cur * 4096;
    bf16x8 af[4], bfr[4];
    #pragma unroll
    for (int i = 0; i < 4; ++i) {
      int row = wm * 64 + i * 16 + l16;
      int slot = quad ^ (row & 3);         // involution of the stage swizzle
      af[i] = *(const bf16x8*)(Ac + row * 32 + slot * 8);
    }
    #pragma unroll
    for (int j = 0; j < 4; ++j) {
      int row = wn * 64 + j * 16 + l16;
      int slot = quad ^ (row & 3);
      bfr[j] = *(const bf16x8*)(Bc + row * 32 + slot * 8);
    }
    #pragma unroll
    for (int i = 0; i < 4; ++i)
      #pragma unroll
      for (int j = 0; j < 4; ++j)
        acc[i][j] = __builtin_amdgcn_mfma_f32_16x16x32_bf16(af[i], bfr[j], acc[i][j], 0, 0, 0);
  }
}

// 128x64 ping-pong core -- kept for the output GEMM (proven, small share).
__device__ __forceinline__ void gemm_core_1024(
    const unsigned short* __restrict__ A, const unsigned short* __restrict__ Bt,
    unsigned short* As, unsigned short* Bs, f32x4 (&acc)[2][4],
    int m0, int n0) {
  const int tid = threadIdx.x;
  const int wave = tid >> 6, lane = tid & 63;
  const int quad = lane >> 4, l16 = lane & 15;
  const int srow = tid >> 3, sc = tid & 7;

  auto stage = [&](int k0, int buf) {
    unsigned short* Ad = As + buf * 8192;
    unsigned short* Bd = Bs + buf * 4096;
    #pragma unroll
    for (int rd = 0; rd < 4; ++rd) {       // A: 128 rows x 8 chunks
      int row = rd * 32 + srow;
      int cs = sc ^ (row & 7);
      gld_lds16(A + (size_t)(m0 + row) * 1024 + k0 + cs * 8, Ad + row * BK + sc * 8);
    }
    #pragma unroll
    for (int rd = 0; rd < 2; ++rd) {       // B: 64 rows x 8 chunks
      int row = rd * 32 + srow;
      int cs = sc ^ (row & 7);
      gld_lds16(Bt + (size_t)(n0 + row) * 1024 + k0 + cs * 8, Bd + row * BK + sc * 8);
    }
  };

  stage(0, 0);
  for (int k = 0; k < 16; ++k) {
    const int cur = k & 1;
    __syncthreads();
    if (k < 15) stage((k + 1) * BK, cur ^ 1);
    const unsigned short* Ac = As + cur * 8192;
    const unsigned short* Bc = Bs + cur * 4096;
    #pragma unroll
    for (int ks = 0; ks < 2; ++ks) {
      bf16x8 af[2], bfr[4];
      #pragma unroll
      for (int i = 0; i < 2; ++i) {
        int row = wave * 32 + i * 16 + l16;
        int ch = (ks * 4 + quad) ^ (row & 7);
        af[i] = *(const bf16x8*)(Ac + row * BK + ch * 8);
      }
      #pragma unroll
      for (int j = 0; j < 4; ++j) {
        int row = j * 16 + l16;
        int ch = (ks * 4 + quad) ^ (row & 7);
        bfr[j] = *(const bf16x8*)(Bc + row * BK + ch * 8);
      }
      #pragma unroll
      for (int i = 0; i < 2; ++i)
        #pragma unroll
        for (int j = 0; j < 4; ++j)
          acc[i][j] = __builtin_amdgcn_mfma_f32_16x16x32_bf16(af[i], bfr[j], acc[i][j], 0, 0, 0);
    }
  }
}

// Projection GEMM with fused epilogues (RoPE for q/k, V-transpose for v).
// Grid 768; XCD decode: each XCD gets 12 (m,z)-groups x 8 n-strips of 128.
struct ProjArgs {
  const unsigned short* A[3];
  const unsigned short* Bt[3];
  unsigned short* C[3];
};
__global__ __launch_bounds__(256) void gemm_proj_kernel(ProjArgs pa) {
  __shared__ unsigned short SH[16384];   // As dbuf (16KB) + Bs dbuf (16KB) = 32KB
  unsigned short* As = SH;
  unsigned short* Bs = SH + 8192;

  const int bflat = blockIdx.x;
  const int xcd = bflat & 7, s = bflat >> 3;      // s: 0..95
  const int nblk = s & 7;                         // 128-wide n strip (2 heads)
  const int mz = xcd * 12 + (s >> 3);             // 0..95
  const int z = mz >> 5;                          // input select
  const int mblk = mz & 31;
  const int m0 = mblk * BM, n0 = nblk * 128;

  f32x4 acc[4][4] = {};
  gemm_core_128x128_bk32(pa.A[z], pa.Bt[z], As, Bs, acc, m0, n0);

  const int tid = threadIdx.x;
  const int lane = tid & 63, wave = tid >> 6;
  const int quad = lane >> 4, l16 = lane & 15;
  const int wm = wave >> 1, wn = wave & 1;
  const int h = nblk * 2 + wn;                    // wave-uniform head

  if (z < 2) {
    // -------- RoPE + scatter to (B,H,L,DH) --------
    float frev[4];
    #pragma unroll
    for (int j = 0; j < 4; ++j) {
      int d = j * 16 + l16;
      frev[j] = exp2f(-(float)(d >> 1) * 0.41524101186092029f) * 0.15915494309189535f;
    }
    unsigned short* C = pa.C[z];
    const bool even = (l16 & 1) == 0;
    #pragma unroll
    for (int i = 0; i < 4; ++i)
      #pragma unroll
      for (int r = 0; r < 4; ++r) {
        int m = m0 + wm * 64 + i * 16 + quad * 4 + r;
        int b = m >> 11, l = m & (L_ - 1);
        float lf = (float)l;
        #pragma unroll
        for (int j = 0; j < 4; ++j) {
          int d = j * 16 + l16;
          float v = acc[i][j][r];
          float p = __shfl_xor(v, 1);       // partner at d^1
          float a = lf * frev[j];
          float t = a - floorf(a);          // revolutions in [0,1)
          float sn = __builtin_amdgcn_sinf(t);
          float cs = __builtin_amdgcn_cosf(t);
          float o = even ? (v * cs - p * sn) : (p * sn + v * cs);
          C[(((size_t)b * H_ + h) * L_ + l) * DH_ + d] = f2bf(o);
        }
      }
  } else {
    // -------- V: per-wave 64(d) x 64(m) transpose via LDS, store (B,H,DH,L) --------
    __syncthreads();   // last-iter readers done; SH free; wave-private 8KB each
    char* T = (char*)SH + wave * 8192;
    #pragma unroll
    for (int i = 0; i < 4; ++i)
      #pragma unroll
      for (int j = 0; j < 4; ++j) {
        int d = j * 16 + l16;
        int mb = i * 32 + quad * 8;                 // byte offset in 128B m-row
        int ch = mb >> 4, sub = mb & 15;
        uint2 pk;
        pk.x = (unsigned)f2bf(acc[i][j][0]) | ((unsigned)f2bf(acc[i][j][1]) << 16);
        pk.y = (unsigned)f2bf(acc[i][j][2]) | ((unsigned)f2bf(acc[i][j][3]) << 16);
        *(uint2*)(T + d * 128 + ((ch ^ (d & 7)) << 4) + sub) = pk;  // ds_write_b64
      }
    asm volatile("s_waitcnt lgkmcnt(0)" ::: "memory");  // wave-private: no barrier
    int b = m0 >> 11;
    int lbase = (m0 & (L_ - 1)) + wm * 64;
    unsigned short* C = pa.C[2];
    #pragma unroll
    for (int t = 0; t < 8; ++t) {                   // coalesced: 8 lanes = 128B row
      int d = t * 8 + (lane >> 3);
      int ch = lane & 7;
      uint4 o = *(uint4*)(T + d * 128 + ((ch ^ (d & 7)) << 4));
      *(uint4*)(C + (((size_t)b * H_ + h) * DH_ + d) * L_ + lbase + ch * 8) = o;
    }
  }
}

// Output GEMM: fp32 row-major epilogue straight to d_out.
// Flat grid of 512; XCD-aware decode: each XCD gets 4 m-groups x 16 n.
__global__ __launch_bounds__(256) void gemm_out_kernel(
    const unsigned short* __restrict__ A, const unsigned short* __restrict__ Bt,
    float* __restrict__ C) {
  __shared__ unsigned short SH[24576];
  unsigned short* As = SH;
  unsigned short* Bs = SH + 16384;

  const int bflat = blockIdx.x;
  const int xcd = bflat & 7, s = bflat >> 3;      // s: 0..63
  const int nblk = s & 15;
  const int mblk = xcd * 4 + (s >> 4);            // 0..31
  const int m0 = mblk * BM, n0 = nblk * BN;

  f32x4 acc[2][4] = {};
  gemm_core_1024(A, Bt, As, Bs, acc, m0, n0);

  const int lane = threadIdx.x & 63, wave = threadIdx.x >> 6;
  const int quad = lane >> 4, l16 = lane & 15;
  #pragma unroll
  for (int i = 0; i < 2; ++i)
    #pragma unroll
    for (int j = 0; j < 4; ++j)
      #pragma unroll
      for (int r = 0; r < 4; ++r) {
        int m = m0 + wave * 32 + i * 16 + quad * 4 + r;
        int n = n0 + j * 16 + l16;
        C[(size_t)m * DIM_ + n] = acc[i][j][r];
      }
}

// ---------------------------------------------------------------- attention
// R16: R15 structure, V buffer trimmed to exactly 320 keys (40 KB -> 4 blk/CU
// if VGPR allows). gld_lds keeps a LINEAR dest; bank conflicts fixed by
// pre-swizzling the GLOBAL source chunk (gch = ch ^ (row&7)) and applying the
// same involution on the read side (rule: both-sides-or-neither). Zero-P tail
// quads (g==8, quad>=2) clamp their V chunk into range (any finite data x 0).
#define VSTR 320
__global__ __launch_bounds__(256) void attn_kernel(
    const unsigned short* __restrict__ Qh,  // (B,H,L,DH) roped
    const unsigned short* __restrict__ Kh,  // (B,H,L,DH) roped
    const unsigned short* __restrict__ Vt,  // (B,H,DH,L)
    unsigned short* __restrict__ O) {       // (B,L,H*DH) bf16
  __shared__ unsigned short Vs[64 * VSTR];  // 40960 B exactly
  const int tid = threadIdx.x;
  const int wave = tid >> 6, lane = tid & 63;
  const int quad = lane >> 4, l16 = lane & 15;

  const int bflat = blockIdx.x;
  const int xcd = bflat & 7, s = bflat >> 3;  // s: 0..127
  const int qt = s >> 2;                      // 0..31 q-tile (64 queries)
  const int bh = xcd * 4 + (s & 3);           // 0..31

  const int q0 = qt * 64;
  const int qb = q0 + wave * 16;              // this wave's 16 queries
  const int kw0 = qb - WWIN;                  // per-wave window start
  const bool edge = (kw0 < 0);

  // ---- stage V via global_load_lds: 64 d-rows x 40 chunks, keys [q0-256,q0+63]
  // Source chunk pre-swizzled: LDS slot ch holds global chunk ch^(row&7).
  const unsigned short* vbase = Vt + (size_t)bh * DH_ * L_;
  #pragma unroll
  for (int it = 0; it < 10; ++it) {         // 2560 = 64*40 chunks, exact
    int ci = it * 256 + tid;
    int row = ci / 40, ch = ci - row * 40;
    int gch = ch ^ (row & 7);               // stays in [0,40): 8-aligned blocks
    int key0 = q0 - WWIN + gch * 8;
    key0 = key0 < 0 ? 0 : key0;             // edge tiles: finite data, P=0 there
    gld_lds16(vbase + (size_t)row * L_ + key0, Vs + ci * 8);
  }

  // ---- Q fragments (B-operand: lane l16 = q-col, quad*8+j = d) ----
  bf16x8 qf0, qf1;
  {
    const unsigned short* qrow = Qh + ((size_t)bh * L_ + qb + l16) * DH_;
    qf0 = *(const bf16x8*)(qrow + quad * 8);
    qf1 = *(const bf16x8*)(qrow + 32 + quad * 8);
  }

  // ---- S^T = K Q^T: 17 static chunks, K direct from global ----
  // D layout: col=l16 = q, row=quad*4+r = key-within-chunk.
  f32x4 S[17] = {};
  const unsigned short* kbase = Kh + (size_t)bh * L_ * DH_;
  #pragma unroll
  for (int c = 0; c < 17; ++c) {
    int key = kw0 + c * 16 + l16;
    key = key < 0 ? 0 : key;                // clamp: finite garbage, masked pre-exp
    const unsigned short* kr = kbase + (size_t)key * DH_ + quad * 8;
    bf16x8 kf0 = *(const bf16x8*)(kr);
    bf16x8 kf1 = *(const bf16x8*)(kr + 32);
    S[c] = __builtin_amdgcn_mfma_f32_16x16x32_bf16(kf0, qf0, S[c], 0, 0, 0);
    S[c] = __builtin_amdgcn_mfma_f32_16x16x32_bf16(kf1, qf1, S[c], 0, 0, 0);
  }

  // ---- masks (lane q = l16; key offset off16 = quad*4 + r) ----
  const int off16 = quad * 4;
  #pragma unroll
  for (int r = 0; r < 4; ++r) {
    if (off16 + r < l16)  S[0][r]  = -1e30f;   // window lower bound
    if (off16 + r > l16)  S[16][r] = -1e30f;   // causal upper bound
  }
  if (edge) {
    #pragma unroll
    for (int c = 0; c < 17; ++c)
      #pragma unroll
      for (int r = 0; r < 4; ++r)
        if (kw0 + c * 16 + off16 + r < 0) S[c][r] = -1e30f;
  }

  // ---- softmax: reduce over (c, r) in-lane, then across quads ----
  float mx = -1e30f;
  #pragma unroll
  for (int c = 0; c < 17; ++c)
    #pragma unroll
    for (int r = 0; r < 4; ++r)
      mx = fmaxf(mx, S[c][r]);
  mx = fmaxf(mx, __shfl_xor(mx, 16));
  mx = fmaxf(mx, __shfl_xor(mx, 32));
  float sum = 0.f;
  #pragma unroll
  for (int c = 0; c < 17; ++c)
    #pragma unroll
    for (int r = 0; r < 4; ++r) {
      // exp(0.125*(S-mx)) = exp2((S-mx) * 0.125*log2(e))
      float e = __builtin_amdgcn_exp2f((S[c][r] - mx) * 0.18033688011112042f);
      S[c][r] = e;
      sum += e;
    }
  sum += __shfl_xor(sum, 16);
  sum += __shfl_xor(sum, 32);
  const float ivl = 1.0f / sum;

  __syncthreads();                          // drains vmcnt: all V staged

  // ---- O = P V: build A-fragment in registers, V from LDS ----
  // Lane (l16,quad) needs P[q=l16][key=32g+8*quad+j]; source regs live at
  // quads 2*(quad&1), 2*(quad&1)+1 with chunk c' = 2g + (quad>>1).
  f32x4 Oacc[4] = {};
  const int srcA = (lane & 15) | ((lane & 16) << 1);   // quad 0 or 2
  const int srcB = srcA + 16;                          // quad 1 or 3
  const bool loq = quad < 2;
  #pragma unroll
  for (int g = 0; g < 9; ++g) {
    unsigned uA0, uA1, uB0, uB1;
    {
      float a0 = S[2 * g][0] * ivl, a1 = S[2 * g][1] * ivl;
      float a2 = S[2 * g][2] * ivl, a3 = S[2 * g][3] * ivl;
      asm("v_cvt_pk_bf16_f32 %0, %1, %2" : "=v"(uA0) : "v"(a0), "v"(a1));
      asm("v_cvt_pk_bf16_f32 %0, %1, %2" : "=v"(uA1) : "v"(a2), "v"(a3));
    }
    if (g < 8) {
      float b0 = S[2 * g + 1][0] * ivl, b1 = S[2 * g + 1][1] * ivl;
      float b2 = S[2 * g + 1][2] * ivl, b3 = S[2 * g + 1][3] * ivl;
      asm("v_cvt_pk_bf16_f32 %0, %1, %2" : "=v"(uB0) : "v"(b0), "v"(b1));
      asm("v_cvt_pk_bf16_f32 %0, %1, %2" : "=v"(uB1) : "v"(b2), "v"(b3));
    } else {
      uB0 = 0; uB1 = 0;                     // tail keys: P = 0
    }
    unsigned tA0a = __shfl(uA0, srcA), tA1a = __shfl(uA1, srcA);
    unsigned tB0a = __shfl(uB0, srcA), tB1a = __shfl(uB1, srcA);
    unsigned tA0b = __shfl(uA0, srcB), tA1b = __shfl(uA1, srcB);
    unsigned tB0b = __shfl(uB0, srcB), tB1b = __shfl(uB1, srcB);
    union { unsigned u[4]; bf16x8 v; } pav;
    pav.u[0] = loq ? tA0a : tB0a;
    pav.u[1] = loq ? tA1a : tB1a;
    pav.u[2] = loq ? tA0b : tB0b;
    pav.u[3] = loq ? tA1b : tB1b;
    // V read: global chunk C -> LDS slot C^(row&7); zero-P tail clamps in-range
    int C = wave * 2 + g * 4 + quad;
    if (g == 8) C = C > 39 ? 39 : C;        // only quads>=2 (P=0) can exceed
    #pragma unroll
    for (int t = 0; t < 4; ++t) {
      int row = t * 16 + l16;
      int slot = C ^ (row & 7);
      bf16x8 vf = *(const bf16x8*)(&Vs[row * VSTR + slot * 8]);
      Oacc[t] = __builtin_amdgcn_mfma_f32_16x16x32_bf16(pav.v, vf, Oacc[t], 0, 0, 0);
    }
  }

  // epilogue: (B, L, H*DH) bf16; D: row=quad*4+r = q, col=l16 (+16t) = d
  int b = bh >> 4, h = bh & 15;
  #pragma unroll
  for (int t = 0; t < 4; ++t)
    #pragma unroll
    for (int r = 0; r < 4; ++r) {
      int l = qb + quad * 4 + r;
      int col = h * DH_ + t * 16 + l16;
      O[((size_t)b * L_ + l) * (H_ * DH_) + col] = f2bf(Oacc[t][r]);
    }
}

// ---------------------------------------------------------------- launch
extern "C" void kernel_launch(void* const* d_in, const int* in_sizes, int n_in,
                              void* d_out, int out_size, void* d_ws, size_t ws_size,
                              hipStream_t stream) {
  const float* q  = (const float*)d_in[0];
  const float* k  = (const float*)d_in[1];
  const float* v  = (const float*)d_in[2];
  const float* wq = (const float*)d_in[3];
  const float* wk = (const float*)d_in[4];
  const float* wv = (const float*)d_in[5];
  const float* wo = (const float*)d_in[6];

  const size_t SA = (size_t)B_ * L_ * DIM_;  // 4,194,304
  const size_t SW = (size_t)DIM_ * DIM_;     // 1,048,576
  unsigned short* w   = (unsigned short*)d_ws;
  unsigned short* qb  = w; w += SA;
  unsigned short* kb  = w; w += SA;
  unsigned short* vb  = w; w += SA;
  unsigned short* wqb = w; w += SW;
  unsigned short* wkb = w; w += SW;
  unsigned short* wvb = w; w += SW;
  unsigned short* wob = w; w += SW;
  unsigned short* qh  = w; w += SA;   // (B,H,L,DH) roped
  unsigned short* kh  = w; w += SA;   // (B,H,L,DH) roped
  unsigned short* vt  = w; w += SA;   // (B,H,DH,L)
  unsigned short* Ob  = w; w += SA;   // (B,L,H*DH)

  CastArgs ca;
  ca.src[0] = q;  ca.dst[0] = qb;
  ca.src[1] = k;  ca.dst[1] = kb;
  ca.src[2] = v;  ca.dst[2] = vb;
  ca.src[3] = wq; ca.dst[3] = wqb;
  ca.src[4] = wk; ca.dst[4] = wkb;
  ca.src[5] = wv; ca.dst[5] = wvb;
  ca.src[6] = wo; ca.dst[6] = wob;
  cast_bf16_kernel<<<dim3(16384), 256, 0, stream>>>(ca);

  ProjArgs pa;
  pa.A[0] = qb; pa.Bt[0] = wqb; pa.C[0] = qh;
  pa.A[1] = kb; pa.Bt[1] = wkb; pa.C[1] = kh;
  pa.A[2] = vb; pa.Bt[2] = wvb; pa.C[2] = vt;
  gemm_proj_kernel<<<dim3(768), 256, 0, stream>>>(pa);

  attn_kernel<<<dim3(32 * 32), 256, 0, stream>>>(qh, kh, vt, Ob);
  gemm_out_kernel<<<dim3(16 * 32), 256, 0, stream>>>(Ob, wob, (float*)d_out);
}

// Round 10
// 182.004 us; speedup vs baseline: 1.0415x; 1.0415x over previous
//
#include <hip/hip_runtime.h>
#include <stdint.h>

// Problem constants (B, L, DIM) = (2, 2048, 1024); H=16, DH=64, W=256.
#define B_    2
#define L_    2048
#define DIM_  1024
#define H_    16
#define DH_   64
#define WWIN  256

typedef __attribute__((ext_vector_type(4))) float f32x4;
typedef __attribute__((ext_vector_type(8))) short bf16x8;

__device__ __forceinline__ unsigned short f2bf(float x) {
  union { float f; unsigned u; } c; c.f = x;
  unsigned r = c.u + 0x7fffu + ((c.u >> 16) & 1u);   // RNE
  return (unsigned short)(r >> 16);
}

// ---------------------------------------------------------------- cast fp32->bf16
// R17: 8 elems/thread (two float4 loads, one 16B store). Exact flat grid:
// 3 activation arrays x 2048 blocks + 4 weight arrays x 512 = 8192 blocks.
struct CastArgs {
  const float* src[7];
  unsigned short* dst[7];
};
__global__ __launch_bounds__(256) void cast_bf16_kernel(CastArgs a) {
  int bid = blockIdx.x;
  int arr, base;
  if (bid < 6144) {             // activations: SA/2048 = 2048 blocks each
    arr = bid >> 11;
    base = (bid & 2047) << 11;
  } else {                      // weights: SW/2048 = 512 blocks each
    int t = bid - 6144;
    arr = 3 + (t >> 9);
    base = (t & 511) << 11;
  }
  int i = base + (int)threadIdx.x * 8;
  float4 v0 = *(const float4*)(a.src[arr] + i);
  float4 v1 = *(const float4*)(a.src[arr] + i + 4);
  union { ushort4 s[2]; uint4 u; } o;
  o.s[0].x = f2bf(v0.x); o.s[0].y = f2bf(v0.y); o.s[0].z = f2bf(v0.z); o.s[0].w = f2bf(v0.w);
  o.s[1].x = f2bf(v1.x); o.s[1].y = f2bf(v1.y); o.s[1].z = f2bf(v1.z); o.s[1].w = f2bf(v1.w);
  *(uint4*)(a.dst[arr] + i) = o.u;
}

// ---------------------------------------------------------------- GEMM C = A @ B^T
// Proven core (R0/R8): tile 128x64 (BM x BN), BK=64; single-barrier ping-pong
// LDS double buffer (48 KB) -> high occupancy. R9's BK=32 128x128 regressed
// (8-way bank conflicts from 64B rows + 2x per-iter address VALU).
#define BM 128
#define BN 64
#define BK 64

__device__ __forceinline__ void gld_lds16(const void* g, void* l) {
  __builtin_amdgcn_global_load_lds(
      (const __attribute__((address_space(1))) void*)g,
      (__attribute__((address_space(3))) void*)l, 16, 0, 0);
}

// As: 2 x 8192 shorts, Bs: 2 x 4096 shorts (ping-pong).
__device__ __forceinline__ void gemm_core_1024(
    const unsigned short* __restrict__ A, const unsigned short* __restrict__ Bt,
    unsigned short* As, unsigned short* Bs, f32x4 (&acc)[2][4],
    int m0, int n0) {
  const int tid = threadIdx.x;
  const int wave = tid >> 6, lane = tid & 63;
  const int quad = lane >> 4, l16 = lane & 15;
  const int srow = tid >> 3, sc = tid & 7;

  auto stage = [&](int k0, int buf) {
    unsigned short* Ad = As + buf * 8192;
    unsigned short* Bd = Bs + buf * 4096;
    #pragma unroll
    for (int rd = 0; rd < 4; ++rd) {       // A: 128 rows x 8 chunks
      int row = rd * 32 + srow;
      int cs = sc ^ (row & 7);             // swizzled global chunk -> linear LDS slot
      gld_lds16(A + (size_t)(m0 + row) * 1024 + k0 + cs * 8, Ad + row * BK + sc * 8);
    }
    #pragma unroll
    for (int rd = 0; rd < 2; ++rd) {       // B: 64 rows x 8 chunks
      int row = rd * 32 + srow;
      int cs = sc ^ (row & 7);
      gld_lds16(Bt + (size_t)(n0 + row) * 1024 + k0 + cs * 8, Bd + row * BK + sc * 8);
    }
  };

  stage(0, 0);
  for (int k = 0; k < 16; ++k) {
    const int cur = k & 1;
    __syncthreads();                       // drains vmcnt -> buf[cur] ready; also
                                           // orders last iter's readers of buf[cur^1]
    if (k < 15) stage((k + 1) * BK, cur ^ 1);
    const unsigned short* Ac = As + cur * 8192;
    const unsigned short* Bc = Bs + cur * 4096;
    #pragma unroll
    for (int ks = 0; ks < 2; ++ks) {
      bf16x8 af[2], bfr[4];
      #pragma unroll
      for (int i = 0; i < 2; ++i) {
        int row = wave * 32 + i * 16 + l16;
        int ch = (ks * 4 + quad) ^ (row & 7);
        af[i] = *(const bf16x8*)(Ac + row * BK + ch * 8);
      }
      #pragma unroll
      for (int j = 0; j < 4; ++j) {
        int row = j * 16 + l16;
        int ch = (ks * 4 + quad) ^ (row & 7);
        bfr[j] = *(const bf16x8*)(Bc + row * BK + ch * 8);
      }
      #pragma unroll
      for (int i = 0; i < 2; ++i)
        #pragma unroll
        for (int j = 0; j < 4; ++j)
          acc[i][j] = __builtin_amdgcn_mfma_f32_16x16x32_bf16(af[i], bfr[j], acc[i][j], 0, 0, 0);
    }
  }
}

// Projection GEMM with fused epilogues (RoPE for q/k, V-transpose for v).
// Flat grid of 1536; XCD-aware decode: each XCD gets 12 (m,z)-groups x 16 n.
struct ProjArgs {
  const unsigned short* A[3];
  const unsigned short* Bt[3];
  unsigned short* C[3];
};
__global__ __launch_bounds__(256) void gemm_proj_kernel(ProjArgs pa) {
  __shared__ unsigned short SH[24576];   // As dbuf (16384) + Bs dbuf (8192) = 48 KB
  unsigned short* As = SH;
  unsigned short* Bs = SH + 16384;

  const int bflat = blockIdx.x;
  const int xcd = bflat & 7, s = bflat >> 3;      // s: 0..191
  const int nblk = s & 15;                        // n strip (also the head h)
  const int mz = xcd * 12 + (s >> 4);             // 0..95
  const int z = mz >> 5;                          // input select
  const int mblk = mz & 31;
  const int m0 = mblk * BM, n0 = nblk * BN;

  f32x4 acc[2][4] = {};
  gemm_core_1024(pa.A[z], pa.Bt[z], As, Bs, acc, m0, n0);

  const int tid = threadIdx.x;
  const int lane = tid & 63, wave = tid >> 6;
  const int quad = lane >> 4, l16 = lane & 15;

  if (z < 2) {
    // -------- RoPE + scatter to (B,H,L,DH); h = nblk is block-uniform --------
    float frev[4];
    #pragma unroll
    for (int j = 0; j < 4; ++j) {
      int d = j * 16 + l16;
      frev[j] = exp2f(-(float)(d >> 1) * 0.41524101186092029f) * 0.15915494309189535f;
    }
    unsigned short* C = pa.C[z];
    const int h = nblk;
    const bool even = (l16 & 1) == 0;
    #pragma unroll
    for (int i = 0; i < 2; ++i)
      #pragma unroll
      for (int r = 0; r < 4; ++r) {
        int m = m0 + wave * 32 + i * 16 + quad * 4 + r;
        int b = m >> 11, l = m & (L_ - 1);
        float lf = (float)l;
        #pragma unroll
        for (int j = 0; j < 4; ++j) {
          int d = j * 16 + l16;
          float v = acc[i][j][r];
          float p = __shfl_xor(v, 1);       // partner at d^1
          float a = lf * frev[j];
          float t = a - floorf(a);          // revolutions in [0,1)
          float sn = __builtin_amdgcn_sinf(t);
          float cs = __builtin_amdgcn_cosf(t);
          float o = even ? (v * cs - p * sn) : (p * sn + v * cs);
          C[(((size_t)b * H_ + h) * L_ + l) * DH_ + d] = f2bf(o);
        }
      }
  } else {
    // -------- V: per-wave 64(n) x 32(m) transpose via LDS, store (B,H,DH,L) --------
    __syncthreads();   // T overlaps dbuf regions other waves may still be reading
    unsigned short* T = SH + wave * 2304;   // 64 rows x 36 shorts (pad: 72B stride)
    #pragma unroll
    for (int i = 0; i < 2; ++i)
      #pragma unroll
      for (int j = 0; j < 4; ++j) {
        int nw = j * 16 + l16;
        int hm = i * 4 + quad;                      // 4-short group in m (0..7)
        uint2 pk;
        pk.x = (unsigned)f2bf(acc[i][j][0]) | ((unsigned)f2bf(acc[i][j][1]) << 16);
        pk.y = (unsigned)f2bf(acc[i][j][2]) | ((unsigned)f2bf(acc[i][j][3]) << 16);
        *(uint2*)(T + nw * 36 + hm * 4) = pk;       // ds_write_b64
      }
    asm volatile("s_waitcnt lgkmcnt(0)" ::: "memory");  // wave-private: no barrier
    int h = nblk;                                   // BN=64: one head per block
    int d = lane;
    int b = m0 >> 11;
    int lbase = (m0 & (L_ - 1)) + wave * 32;
    unsigned short* C = pa.C[2];
    size_t rowbase = (((size_t)b * H_ + h) * DH_ + d) * L_ + lbase;
    #pragma unroll
    for (int t = 0; t < 4; ++t) {
      uint2 lo = *(uint2*)(T + lane * 36 + t * 8);
      uint2 hi = *(uint2*)(T + lane * 36 + t * 8 + 4);
      uint4 o = {lo.x, lo.y, hi.x, hi.y};           // m-local [8t, 8t+8)
      *(uint4*)(C + rowbase + t * 8) = o;
    }
  }
}

// Output GEMM: fp32 row-major epilogue straight to d_out.
// Flat grid of 512; XCD-aware decode: each XCD gets 4 m-groups x 16 n.
__global__ __launch_bounds__(256) void gemm_out_kernel(
    const unsigned short* __restrict__ A, const unsigned short* __restrict__ Bt,
    float* __restrict__ C) {
  __shared__ unsigned short SH[24576];
  unsigned short* As = SH;
  unsigned short* Bs = SH + 16384;

  const int bflat = blockIdx.x;
  const int xcd = bflat & 7, s = bflat >> 3;      // s: 0..63
  const int nblk = s & 15;
  const int mblk = xcd * 4 + (s >> 4);            // 0..31
  const int m0 = mblk * BM, n0 = nblk * BN;

  f32x4 acc[2][4] = {};
  gemm_core_1024(A, Bt, As, Bs, acc, m0, n0);

  const int lane = threadIdx.x & 63, wave = threadIdx.x >> 6;
  const int quad = lane >> 4, l16 = lane & 15;
  #pragma unroll
  for (int i = 0; i < 2; ++i)
    #pragma unroll
    for (int j = 0; j < 4; ++j)
      #pragma unroll
      for (int r = 0; r < 4; ++r) {
        int m = m0 + wave * 32 + i * 16 + quad * 4 + r;
        int n = n0 + j * 16 + l16;
        C[(size_t)m * DIM_ + n] = acc[i][j][r];
      }
}

// ---------------------------------------------------------------- attention
// R16 (kept): V staged via global_load_lds into exactly 40 KB (4 blocks/CU);
// bank conflicts handled by pre-swizzling the GLOBAL source chunk and applying
// the same involution on the read side. Swapped QK^T (S^T = mfma(K,Q)); P ->
// PV A-fragment in registers via v_cvt_pk_bf16_f32 + shuffles; one barrier.
#define VSTR 320
__global__ __launch_bounds__(256) void attn_kernel(
    const unsigned short* __restrict__ Qh,  // (B,H,L,DH) roped
    const unsigned short* __restrict__ Kh,  // (B,H,L,DH) roped
    const unsigned short* __restrict__ Vt,  // (B,H,DH,L)
    unsigned short* __restrict__ O) {       // (B,L,H*DH) bf16
  __shared__ unsigned short Vs[64 * VSTR];  // 40960 B exactly
  const int tid = threadIdx.x;
  const int wave = tid >> 6, lane = tid & 63;
  const int quad = lane >> 4, l16 = lane & 15;

  const int bflat = blockIdx.x;
  const int xcd = bflat & 7, s = bflat >> 3;  // s: 0..127
  const int qt = s >> 2;                      // 0..31 q-tile (64 queries)
  const int bh = xcd * 4 + (s & 3);           // 0..31

  const int q0 = qt * 64;
  const int qb = q0 + wave * 16;              // this wave's 16 queries
  const int kw0 = qb - WWIN;                  // per-wave window start
  const bool edge = (kw0 < 0);

  // ---- stage V via global_load_lds: 64 d-rows x 40 chunks, keys [q0-256,q0+63]
  // Source chunk pre-swizzled: LDS slot ch holds global chunk ch^(row&7).
  const unsigned short* vbase = Vt + (size_t)bh * DH_ * L_;
  #pragma unroll
  for (int it = 0; it < 10; ++it) {         // 2560 = 64*40 chunks, exact
    int ci = it * 256 + tid;
    int row = ci / 40, ch = ci - row * 40;
    int gch = ch ^ (row & 7);               // stays in [0,40): 8-aligned blocks
    int key0 = q0 - WWIN + gch * 8;
    key0 = key0 < 0 ? 0 : key0;             // edge tiles: finite data, P=0 there
    gld_lds16(vbase + (size_t)row * L_ + key0, Vs + ci * 8);
  }

  // ---- Q fragments (B-operand: lane l16 = q-col, quad*8+j = d) ----
  bf16x8 qf0, qf1;
  {
    const unsigned short* qrow = Qh + ((size_t)bh * L_ + qb + l16) * DH_;
    qf0 = *(const bf16x8*)(qrow + quad * 8);
    qf1 = *(const bf16x8*)(qrow + 32 + quad * 8);
  }

  // ---- S^T = K Q^T: 17 static chunks, K direct from global ----
  // D layout: col=l16 = q, row=quad*4+r = key-within-chunk.
  f32x4 S[17] = {};
  const unsigned short* kbase = Kh + (size_t)bh * L_ * DH_;
  #pragma unroll
  for (int c = 0; c < 17; ++c) {
    int key = kw0 + c * 16 + l16;
    key = key < 0 ? 0 : key;                // clamp: finite garbage, masked pre-exp
    const unsigned short* kr = kbase + (size_t)key * DH_ + quad * 8;
    bf16x8 kf0 = *(const bf16x8*)(kr);
    bf16x8 kf1 = *(const bf16x8*)(kr + 32);
    S[c] = __builtin_amdgcn_mfma_f32_16x16x32_bf16(kf0, qf0, S[c], 0, 0, 0);
    S[c] = __builtin_amdgcn_mfma_f32_16x16x32_bf16(kf1, qf1, S[c], 0, 0, 0);
  }

  // ---- masks (lane q = l16; key offset off16 = quad*4 + r) ----
  const int off16 = quad * 4;
  #pragma unroll
  for (int r = 0; r < 4; ++r) {
    if (off16 + r < l16)  S[0][r]  = -1e30f;   // window lower bound
    if (off16 + r > l16)  S[16][r] = -1e30f;   // causal upper bound
  }
  if (edge) {
    #pragma unroll
    for (int c = 0; c < 17; ++c)
      #pragma unroll
      for (int r = 0; r < 4; ++r)
        if (kw0 + c * 16 + off16 + r < 0) S[c][r] = -1e30f;
  }

  // ---- softmax: reduce over (c, r) in-lane, then across quads ----
  float mx = -1e30f;
  #pragma unroll
  for (int c = 0; c < 17; ++c)
    #pragma unroll
    for (int r = 0; r < 4; ++r)
      mx = fmaxf(mx, S[c][r]);
  mx = fmaxf(mx, __shfl_xor(mx, 16));
  mx = fmaxf(mx, __shfl_xor(mx, 32));
  float sum = 0.f;
  #pragma unroll
  for (int c = 0; c < 17; ++c)
    #pragma unroll
    for (int r = 0; r < 4; ++r) {
      // exp(0.125*(S-mx)) = exp2((S-mx) * 0.125*log2(e))
      float e = __builtin_amdgcn_exp2f((S[c][r] - mx) * 0.18033688011112042f);
      S[c][r] = e;
      sum += e;
    }
  sum += __shfl_xor(sum, 16);
  sum += __shfl_xor(sum, 32);
  const float ivl = 1.0f / sum;

  __syncthreads();                          // drains vmcnt: all V staged

  // ---- O = P V: build A-fragment in registers, V from LDS ----
  // Lane (l16,quad) needs P[q=l16][key=32g+8*quad+j]; source regs live at
  // quads 2*(quad&1), 2*(quad&1)+1 with chunk c' = 2g + (quad>>1).
  f32x4 Oacc[4] = {};
  const int srcA = (lane & 15) | ((lane & 16) << 1);   // quad 0 or 2
  const int srcB = srcA + 16;                          // quad 1 or 3
  const bool loq = quad < 2;
  #pragma unroll
  for (int g = 0; g < 9; ++g) {
    unsigned uA0, uA1, uB0, uB1;
    {
      float a0 = S[2 * g][0] * ivl, a1 = S[2 * g][1] * ivl;
      float a2 = S[2 * g][2] * ivl, a3 = S[2 * g][3] * ivl;
      asm("v_cvt_pk_bf16_f32 %0, %1, %2" : "=v"(uA0) : "v"(a0), "v"(a1));
      asm("v_cvt_pk_bf16_f32 %0, %1, %2" : "=v"(uA1) : "v"(a2), "v"(a3));
    }
    if (g < 8) {
      float b0 = S[2 * g + 1][0] * ivl, b1 = S[2 * g + 1][1] * ivl;
      float b2 = S[2 * g + 1][2] * ivl, b3 = S[2 * g + 1][3] * ivl;
      asm("v_cvt_pk_bf16_f32 %0, %1, %2" : "=v"(uB0) : "v"(b0), "v"(b1));
      asm("v_cvt_pk_bf16_f32 %0, %1, %2" : "=v"(uB1) : "v"(b2), "v"(b3));
    } else {
      uB0 = 0; uB1 = 0;                     // tail keys: P = 0
    }
    unsigned tA0a = __shfl(uA0, srcA), tA1a = __shfl(uA1, srcA);
    unsigned tB0a = __shfl(uB0, srcA), tB1a = __shfl(uB1, srcA);
    unsigned tA0b = __shfl(uA0, srcB), tA1b = __shfl(uA1, srcB);
    unsigned tB0b = __shfl(uB0, srcB), tB1b = __shfl(uB1, srcB);
    union { unsigned u[4]; bf16x8 v; } pav;
    pav.u[0] = loq ? tA0a : tB0a;
    pav.u[1] = loq ? tA1a : tB1a;
    pav.u[2] = loq ? tA0b : tB0b;
    pav.u[3] = loq ? tA1b : tB1b;
    // V read: global chunk C -> LDS slot C^(row&7); zero-P tail clamps in-range
    int C = wave * 2 + g * 4 + quad;
    if (g == 8) C = C > 39 ? 39 : C;        // only quads>=2 (P=0) can exceed
    #pragma unroll
    for (int t = 0; t < 4; ++t) {
      int row = t * 16 + l16;
      int slot = C ^ (row & 7);
      bf16x8 vf = *(const bf16x8*)(&Vs[row * VSTR + slot * 8]);
      Oacc[t] = __builtin_amdgcn_mfma_f32_16x16x32_bf16(pav.v, vf, Oacc[t], 0, 0, 0);
    }
  }

  // epilogue: (B, L, H*DH) bf16; D: row=quad*4+r = q, col=l16 (+16t) = d
  int b = bh >> 4, h = bh & 15;
  #pragma unroll
  for (int t = 0; t < 4; ++t)
    #pragma unroll
    for (int r = 0; r < 4; ++r) {
      int l = qb + quad * 4 + r;
      int col = h * DH_ + t * 16 + l16;
      O[((size_t)b * L_ + l) * (H_ * DH_) + col] = f2bf(Oacc[t][r]);
    }
}

// ---------------------------------------------------------------- launch
extern "C" void kernel_launch(void* const* d_in, const int* in_sizes, int n_in,
                              void* d_out, int out_size, void* d_ws, size_t ws_size,
                              hipStream_t stream) {
  const float* q  = (const float*)d_in[0];
  const float* k  = (const float*)d_in[1];
  const float* v  = (const float*)d_in[2];
  const float* wq = (const float*)d_in[3];
  const float* wk = (const float*)d_in[4];
  const float* wv = (const float*)d_in[5];
  const float* wo = (const float*)d_in[6];

  const size_t SA = (size_t)B_ * L_ * DIM_;  // 4,194,304
  const size_t SW = (size_t)DIM_ * DIM_;     // 1,048,576
  unsigned short* w   = (unsigned short*)d_ws;
  unsigned short* qb  = w; w += SA;
  unsigned short* kb  = w; w += SA;
  unsigned short* vb  = w; w += SA;
  unsigned short* wqb = w; w += SW;
  unsigned short* wkb = w; w += SW;
  unsigned short* wvb = w; w += SW;
  unsigned short* wob = w; w += SW;
  unsigned short* qh  = w; w += SA;   // (B,H,L,DH) roped
  unsigned short* kh  = w; w += SA;   // (B,H,L,DH) roped
  unsigned short* vt  = w; w += SA;   // (B,H,DH,L)
  unsigned short* Ob  = w; w += SA;   // (B,L,H*DH)

  CastArgs ca;
  ca.src[0] = q;  ca.dst[0] = qb;
  ca.src[1] = k;  ca.dst[1] = kb;
  ca.src[2] = v;  ca.dst[2] = vb;
  ca.src[3] = wq; ca.dst[3] = wqb;
  ca.src[4] = wk; ca.dst[4] = wkb;
  ca.src[5] = wv; ca.dst[5] = wvb;
  ca.src[6] = wo; ca.dst[6] = wob;
  cast_bf16_kernel<<<dim3(8192), 256, 0, stream>>>(ca);

  ProjArgs pa;
  pa.A[0] = qb; pa.Bt[0] = wqb; pa.C[0] = qh;
  pa.A[1] = kb; pa.Bt[1] = wkb; pa.C[1] = kh;
  pa.A[2] = vb; pa.Bt[2] = wvb; pa.C[2] = vt;
  gemm_proj_kernel<<<dim3(16 * 32 * 3), 256, 0, stream>>>(pa);

  attn_kernel<<<dim3(32 * 32), 256, 0, stream>>>(qh, kh, vt, Ob);
  gemm_out_kernel<<<dim3(16 * 32), 256, 0, stream>>>(Ob, wob, (float*)d_out);
}

// Round 11
// 180.042 us; speedup vs baseline: 1.0529x; 1.0109x over previous
//
#include <hip/hip_runtime.h>
#include <stdint.h>

// Problem constants (B, L, DIM) = (2, 2048, 1024); H=16, DH=64, W=256.
#define B_    2
#define L_    2048
#define DIM_  1024
#define H_    16
#define DH_   64
#define WWIN  256

typedef __attribute__((ext_vector_type(4))) float f32x4;
typedef __attribute__((ext_vector_type(8))) short bf16x8;

__device__ __forceinline__ unsigned short f2bf(float x) {
  union { float f; unsigned u; } c; c.f = x;
  unsigned r = c.u + 0x7fffu + ((c.u >> 16) & 1u);   // RNE
  return (unsigned short)(r >> 16);
}

// ---------------------------------------------------------------- cast fp32->bf16
// 8 elems/thread (two float4 loads, one 16B store). Exact flat grid:
// 3 activation arrays x 2048 blocks + 4 weight arrays x 512 = 8192 blocks.
struct CastArgs {
  const float* src[7];
  unsigned short* dst[7];
};
__global__ __launch_bounds__(256) void cast_bf16_kernel(CastArgs a) {
  int bid = blockIdx.x;
  int arr, base;
  if (bid < 6144) {             // activations: SA/2048 = 2048 blocks each
    arr = bid >> 11;
    base = (bid & 2047) << 11;
  } else {                      // weights: SW/2048 = 512 blocks each
    int t = bid - 6144;
    arr = 3 + (t >> 9);
    base = (t & 511) << 11;
  }
  int i = base + (int)threadIdx.x * 8;
  float4 v0 = *(const float4*)(a.src[arr] + i);
  float4 v1 = *(const float4*)(a.src[arr] + i + 4);
  union { ushort4 s[2]; uint4 u; } o;
  o.s[0].x = f2bf(v0.x); o.s[0].y = f2bf(v0.y); o.s[0].z = f2bf(v0.z); o.s[0].w = f2bf(v0.w);
  o.s[1].x = f2bf(v1.x); o.s[1].y = f2bf(v1.y); o.s[1].z = f2bf(v1.z); o.s[1].w = f2bf(v1.w);
  *(uint4*)(a.dst[arr] + i) = o.u;
}

// ---------------------------------------------------------------- GEMM C = A @ B^T
// Proven core (R0/R8): tile 128x64 (BM x BN), BK=64; single-barrier ping-pong
// LDS double buffer (48 KB) -> high occupancy.
#define BM 128
#define BN 64
#define BK 64

__device__ __forceinline__ void gld_lds16(const void* g, void* l) {
  __builtin_amdgcn_global_load_lds(
      (const __attribute__((address_space(1))) void*)g,
      (__attribute__((address_space(3))) void*)l, 16, 0, 0);
}

// As: 2 x 8192 shorts, Bs: 2 x 4096 shorts (ping-pong).
__device__ __forceinline__ void gemm_core_1024(
    const unsigned short* __restrict__ A, const unsigned short* __restrict__ Bt,
    unsigned short* As, unsigned short* Bs, f32x4 (&acc)[2][4],
    int m0, int n0) {
  const int tid = threadIdx.x;
  const int wave = tid >> 6, lane = tid & 63;
  const int quad = lane >> 4, l16 = lane & 15;
  const int srow = tid >> 3, sc = tid & 7;

  auto stage = [&](int k0, int buf) {
    unsigned short* Ad = As + buf * 8192;
    unsigned short* Bd = Bs + buf * 4096;
    #pragma unroll
    for (int rd = 0; rd < 4; ++rd) {       // A: 128 rows x 8 chunks
      int row = rd * 32 + srow;
      int cs = sc ^ (row & 7);             // swizzled global chunk -> linear LDS slot
      gld_lds16(A + (size_t)(m0 + row) * 1024 + k0 + cs * 8, Ad + row * BK + sc * 8);
    }
    #pragma unroll
    for (int rd = 0; rd < 2; ++rd) {       // B: 64 rows x 8 chunks
      int row = rd * 32 + srow;
      int cs = sc ^ (row & 7);
      gld_lds16(Bt + (size_t)(n0 + row) * 1024 + k0 + cs * 8, Bd + row * BK + sc * 8);
    }
  };

  stage(0, 0);
  for (int k = 0; k < 16; ++k) {
    const int cur = k & 1;
    __syncthreads();                       // drains vmcnt -> buf[cur] ready; also
                                           // orders last iter's readers of buf[cur^1]
    if (k < 15) stage((k + 1) * BK, cur ^ 1);
    const unsigned short* Ac = As + cur * 8192;
    const unsigned short* Bc = Bs + cur * 4096;
    #pragma unroll
    for (int ks = 0; ks < 2; ++ks) {
      bf16x8 af[2], bfr[4];
      #pragma unroll
      for (int i = 0; i < 2; ++i) {
        int row = wave * 32 + i * 16 + l16;
        int ch = (ks * 4 + quad) ^ (row & 7);
        af[i] = *(const bf16x8*)(Ac + row * BK + ch * 8);
      }
      #pragma unroll
      for (int j = 0; j < 4; ++j) {
        int row = j * 16 + l16;
        int ch = (ks * 4 + quad) ^ (row & 7);
        bfr[j] = *(const bf16x8*)(Bc + row * BK + ch * 8);
      }
      #pragma unroll
      for (int i = 0; i < 2; ++i)
        #pragma unroll
        for (int j = 0; j < 4; ++j)
          acc[i][j] = __builtin_amdgcn_mfma_f32_16x16x32_bf16(af[i], bfr[j], acc[i][j], 0, 0, 0);
    }
  }
}

// Projection GEMM with fused epilogues (RoPE for q/k, V-transpose for v).
// Flat grid of 1536; XCD-aware decode: each XCD gets 12 (m,z)-groups x 16 n.
struct ProjArgs {
  const unsigned short* A[3];
  const unsigned short* Bt[3];
  unsigned short* C[3];
};
__global__ __launch_bounds__(256) void gemm_proj_kernel(ProjArgs pa) {
  __shared__ unsigned short SH[24576];   // As dbuf (16384) + Bs dbuf (8192) = 48 KB
  unsigned short* As = SH;
  unsigned short* Bs = SH + 16384;

  const int bflat = blockIdx.x;
  const int xcd = bflat & 7, s = bflat >> 3;      // s: 0..191
  const int nblk = s & 15;                        // n strip (also the head h)
  const int mz = xcd * 12 + (s >> 4);             // 0..95
  const int z = mz >> 5;                          // input select
  const int mblk = mz & 31;
  const int m0 = mblk * BM, n0 = nblk * BN;

  f32x4 acc[2][4] = {};
  gemm_core_1024(pa.A[z], pa.Bt[z], As, Bs, acc, m0, n0);

  const int tid = threadIdx.x;
  const int lane = tid & 63, wave = tid >> 6;
  const int quad = lane >> 4, l16 = lane & 15;

  if (z < 2) {
    // -------- RoPE + scatter to (B,H,L,DH); h = nblk is block-uniform --------
    float frev[4];
    #pragma unroll
    for (int j = 0; j < 4; ++j) {
      int d = j * 16 + l16;
      frev[j] = exp2f(-(float)(d >> 1) * 0.41524101186092029f) * 0.15915494309189535f;
    }
    unsigned short* C = pa.C[z];
    const int h = nblk;
    const bool even = (l16 & 1) == 0;
    #pragma unroll
    for (int i = 0; i < 2; ++i)
      #pragma unroll
      for (int r = 0; r < 4; ++r) {
        int m = m0 + wave * 32 + i * 16 + quad * 4 + r;
        int b = m >> 11, l = m & (L_ - 1);
        float lf = (float)l;
        #pragma unroll
        for (int j = 0; j < 4; ++j) {
          int d = j * 16 + l16;
          float v = acc[i][j][r];
          float p = __shfl_xor(v, 1);       // partner at d^1
          float a = lf * frev[j];
          float t = a - floorf(a);          // revolutions in [0,1)
          float sn = __builtin_amdgcn_sinf(t);
          float cs = __builtin_amdgcn_cosf(t);
          float o = even ? (v * cs - p * sn) : (p * sn + v * cs);
          C[(((size_t)b * H_ + h) * L_ + l) * DH_ + d] = f2bf(o);
        }
      }
  } else {
    // -------- V: per-wave 64(n) x 32(m) transpose via LDS, store (B,H,DH,L) --------
    __syncthreads();   // T overlaps dbuf regions other waves may still be reading
    unsigned short* T = SH + wave * 2304;   // 64 rows x 36 shorts (pad: 72B stride)
    #pragma unroll
    for (int i = 0; i < 2; ++i)
      #pragma unroll
      for (int j = 0; j < 4; ++j) {
        int nw = j * 16 + l16;
        int hm = i * 4 + quad;                      // 4-short group in m (0..7)
        uint2 pk;
        pk.x = (unsigned)f2bf(acc[i][j][0]) | ((unsigned)f2bf(acc[i][j][1]) << 16);
        pk.y = (unsigned)f2bf(acc[i][j][2]) | ((unsigned)f2bf(acc[i][j][3]) << 16);
        *(uint2*)(T + nw * 36 + hm * 4) = pk;       // ds_write_b64
      }
    asm volatile("s_waitcnt lgkmcnt(0)" ::: "memory");  // wave-private: no barrier
    int h = nblk;                                   // BN=64: one head per block
    int d = lane;
    int b = m0 >> 11;
    int lbase = (m0 & (L_ - 1)) + wave * 32;
    unsigned short* C = pa.C[2];
    size_t rowbase = (((size_t)b * H_ + h) * DH_ + d) * L_ + lbase;
    #pragma unroll
    for (int t = 0; t < 4; ++t) {
      uint2 lo = *(uint2*)(T + lane * 36 + t * 8);
      uint2 hi = *(uint2*)(T + lane * 36 + t * 8 + 4);
      uint4 o = {lo.x, lo.y, hi.x, hi.y};           // m-local [8t, 8t+8)
      *(uint4*)(C + rowbase + t * 8) = o;
    }
  }
}

// Output GEMM: fp32 row-major epilogue straight to d_out.
// Flat grid of 512; XCD-aware decode: each XCD gets 4 m-groups x 16 n.
__global__ __launch_bounds__(256) void gemm_out_kernel(
    const unsigned short* __restrict__ A, const unsigned short* __restrict__ Bt,
    float* __restrict__ C) {
  __shared__ unsigned short SH[24576];
  unsigned short* As = SH;
  unsigned short* Bs = SH + 16384;

  const int bflat = blockIdx.x;
  const int xcd = bflat & 7, s = bflat >> 3;      // s: 0..63
  const int nblk = s & 15;
  const int mblk = xcd * 4 + (s >> 4);            // 0..31
  const int m0 = mblk * BM, n0 = nblk * BN;

  f32x4 acc[2][4] = {};
  gemm_core_1024(A, Bt, As, Bs, acc, m0, n0);

  const int lane = threadIdx.x & 63, wave = threadIdx.x >> 6;
  const int quad = lane >> 4, l16 = lane & 15;
  #pragma unroll
  for (int i = 0; i < 2; ++i)
    #pragma unroll
    for (int j = 0; j < 4; ++j)
      #pragma unroll
      for (int r = 0; r < 4; ++r) {
        int m = m0 + wave * 32 + i * 16 + quad * 4 + r;
        int n = n0 + j * 16 + l16;
        C[(size_t)m * DIM_ + n] = acc[i][j][r];
      }
}

// ---------------------------------------------------------------- attention
// R18: R16 structure + (a) __launch_bounds__(256,4): cap VGPR at 128 so the
// exact-fit 40 KB LDS actually yields 4 blocks/CU (16 waves) -- the kernel is
// a latency-chain workload (34 serial K-load->MFMA steps), so resident-chain
// count is the lever; (b) s_setprio(1) around the QK and PV MFMA clusters
// (T5: +4-7% on barrier-light attn, m191).
#define VSTR 320
__global__ __launch_bounds__(256, 4) void attn_kernel(
    const unsigned short* __restrict__ Qh,  // (B,H,L,DH) roped
    const unsigned short* __restrict__ Kh,  // (B,H,L,DH) roped
    const unsigned short* __restrict__ Vt,  // (B,H,DH,L)
    unsigned short* __restrict__ O) {       // (B,L,H*DH) bf16
  __shared__ unsigned short Vs[64 * VSTR];  // 40960 B exactly -> 4 blocks/CU
  const int tid = threadIdx.x;
  const int wave = tid >> 6, lane = tid & 63;
  const int quad = lane >> 4, l16 = lane & 15;

  const int bflat = blockIdx.x;
  const int xcd = bflat & 7, s = bflat >> 3;  // s: 0..127
  const int qt = s >> 2;                      // 0..31 q-tile (64 queries)
  const int bh = xcd * 4 + (s & 3);           // 0..31

  const int q0 = qt * 64;
  const int qb = q0 + wave * 16;              // this wave's 16 queries
  const int kw0 = qb - WWIN;                  // per-wave window start
  const bool edge = (kw0 < 0);

  // ---- stage V via global_load_lds: 64 d-rows x 40 chunks, keys [q0-256,q0+63]
  // Source chunk pre-swizzled: LDS slot ch holds global chunk ch^(row&7).
  const unsigned short* vbase = Vt + (size_t)bh * DH_ * L_;
  #pragma unroll
  for (int it = 0; it < 10; ++it) {         // 2560 = 64*40 chunks, exact
    int ci = it * 256 + tid;
    int row = ci / 40, ch = ci - row * 40;
    int gch = ch ^ (row & 7);               // stays in [0,40): 8-aligned blocks
    int key0 = q0 - WWIN + gch * 8;
    key0 = key0 < 0 ? 0 : key0;             // edge tiles: finite data, P=0 there
    gld_lds16(vbase + (size_t)row * L_ + key0, Vs + ci * 8);
  }

  // ---- Q fragments (B-operand: lane l16 = q-col, quad*8+j = d) ----
  bf16x8 qf0, qf1;
  {
    const unsigned short* qrow = Qh + ((size_t)bh * L_ + qb + l16) * DH_;
    qf0 = *(const bf16x8*)(qrow + quad * 8);
    qf1 = *(const bf16x8*)(qrow + 32 + quad * 8);
  }

  // ---- S^T = K Q^T: 17 static chunks, K direct from global ----
  // D layout: col=l16 = q, row=quad*4+r = key-within-chunk.
  f32x4 S[17] = {};
  const unsigned short* kbase = Kh + (size_t)bh * L_ * DH_;
  __builtin_amdgcn_s_setprio(1);
  #pragma unroll
  for (int c = 0; c < 17; ++c) {
    int key = kw0 + c * 16 + l16;
    key = key < 0 ? 0 : key;                // clamp: finite garbage, masked pre-exp
    const unsigned short* kr = kbase + (size_t)key * DH_ + quad * 8;
    bf16x8 kf0 = *(const bf16x8*)(kr);
    bf16x8 kf1 = *(const bf16x8*)(kr + 32);
    S[c] = __builtin_amdgcn_mfma_f32_16x16x32_bf16(kf0, qf0, S[c], 0, 0, 0);
    S[c] = __builtin_amdgcn_mfma_f32_16x16x32_bf16(kf1, qf1, S[c], 0, 0, 0);
  }
  __builtin_amdgcn_s_setprio(0);

  // ---- masks (lane q = l16; key offset off16 = quad*4 + r) ----
  const int off16 = quad * 4;
  #pragma unroll
  for (int r = 0; r < 4; ++r) {
    if (off16 + r < l16)  S[0][r]  = -1e30f;   // window lower bound
    if (off16 + r > l16)  S[16][r] = -1e30f;   // causal upper bound
  }
  if (edge) {
    #pragma unroll
    for (int c = 0; c < 17; ++c)
      #pragma unroll
      for (int r = 0; r < 4; ++r)
        if (kw0 + c * 16 + off16 + r < 0) S[c][r] = -1e30f;
  }

  // ---- softmax: reduce over (c, r) in-lane, then across quads ----
  float mx = -1e30f;
  #pragma unroll
  for (int c = 0; c < 17; ++c)
    #pragma unroll
    for (int r = 0; r < 4; ++r)
      mx = fmaxf(mx, S[c][r]);
  mx = fmaxf(mx, __shfl_xor(mx, 16));
  mx = fmaxf(mx, __shfl_xor(mx, 32));
  float sum = 0.f;
  #pragma unroll
  for (int c = 0; c < 17; ++c)
    #pragma unroll
    for (int r = 0; r < 4; ++r) {
      // exp(0.125*(S-mx)) = exp2((S-mx) * 0.125*log2(e))
      float e = __builtin_amdgcn_exp2f((S[c][r] - mx) * 0.18033688011112042f);
      S[c][r] = e;
      sum += e;
    }
  sum += __shfl_xor(sum, 16);
  sum += __shfl_xor(sum, 32);
  const float ivl = 1.0f / sum;

  __syncthreads();                          // drains vmcnt: all V staged

  // ---- O = P V: build A-fragment in registers, V from LDS ----
  // Lane (l16,quad) needs P[q=l16][key=32g+8*quad+j]; source regs live at
  // quads 2*(quad&1), 2*(quad&1)+1 with chunk c' = 2g + (quad>>1).
  f32x4 Oacc[4] = {};
  const int srcA = (lane & 15) | ((lane & 16) << 1);   // quad 0 or 2
  const int srcB = srcA + 16;                          // quad 1 or 3
  const bool loq = quad < 2;
  #pragma unroll
  for (int g = 0; g < 9; ++g) {
    unsigned uA0, uA1, uB0, uB1;
    {
      float a0 = S[2 * g][0] * ivl, a1 = S[2 * g][1] * ivl;
      float a2 = S[2 * g][2] * ivl, a3 = S[2 * g][3] * ivl;
      asm("v_cvt_pk_bf16_f32 %0, %1, %2" : "=v"(uA0) : "v"(a0), "v"(a1));
      asm("v_cvt_pk_bf16_f32 %0, %1, %2" : "=v"(uA1) : "v"(a2), "v"(a3));
    }
    if (g < 8) {
      float b0 = S[2 * g + 1][0] * ivl, b1 = S[2 * g + 1][1] * ivl;
      float b2 = S[2 * g + 1][2] * ivl, b3 = S[2 * g + 1][3] * ivl;
      asm("v_cvt_pk_bf16_f32 %0, %1, %2" : "=v"(uB0) : "v"(b0), "v"(b1));
      asm("v_cvt_pk_bf16_f32 %0, %1, %2" : "=v"(uB1) : "v"(b2), "v"(b3));
    } else {
      uB0 = 0; uB1 = 0;                     // tail keys: P = 0
    }
    unsigned tA0a = __shfl(uA0, srcA), tA1a = __shfl(uA1, srcA);
    unsigned tB0a = __shfl(uB0, srcA), tB1a = __shfl(uB1, srcA);
    unsigned tA0b = __shfl(uA0, srcB), tA1b = __shfl(uA1, srcB);
    unsigned tB0b = __shfl(uB0, srcB), tB1b = __shfl(uB1, srcB);
    union { unsigned u[4]; bf16x8 v; } pav;
    pav.u[0] = loq ? tA0a : tB0a;
    pav.u[1] = loq ? tA1a : tB1a;
    pav.u[2] = loq ? tA0b : tB0b;
    pav.u[3] = loq ? tA1b : tB1b;
    // V read: global chunk C -> LDS slot C^(row&7); zero-P tail clamps in-range
    int C = wave * 2 + g * 4 + quad;
    if (g == 8) C = C > 39 ? 39 : C;        // only quads>=2 (P=0) can exceed
    __builtin_amdgcn_s_setprio(1);
    #pragma unroll
    for (int t = 0; t < 4; ++t) {
      int row = t * 16 + l16;
      int slot = C ^ (row & 7);
      bf16x8 vf = *(const bf16x8*)(&Vs[row * VSTR + slot * 8]);
      Oacc[t] = __builtin_amdgcn_mfma_f32_16x16x32_bf16(pav.v, vf, Oacc[t], 0, 0, 0);
    }
    __builtin_amdgcn_s_setprio(0);
  }

  // epilogue: (B, L, H*DH) bf16; D: row=quad*4+r = q, col=l16 (+16t) = d
  int b = bh >> 4, h = bh & 15;
  #pragma unroll
  for (int t = 0; t < 4; ++t)
    #pragma unroll
    for (int r = 0; r < 4; ++r) {
      int l = qb + quad * 4 + r;
      int col = h * DH_ + t * 16 + l16;
      O[((size_t)b * L_ + l) * (H_ * DH_) + col] = f2bf(Oacc[t][r]);
    }
}

// ---------------------------------------------------------------- launch
extern "C" void kernel_launch(void* const* d_in, const int* in_sizes, int n_in,
                              void* d_out, int out_size, void* d_ws, size_t ws_size,
                              hipStream_t stream) {
  const float* q  = (const float*)d_in[0];
  const float* k  = (const float*)d_in[1];
  const float* v  = (const float*)d_in[2];
  const float* wq = (const float*)d_in[3];
  const float* wk = (const float*)d_in[4];
  const float* wv = (const float*)d_in[5];
  const float* wo = (const float*)d_in[6];

  const size_t SA = (size_t)B_ * L_ * DIM_;  // 4,194,304
  const size_t SW = (size_t)DIM_ * DIM_;     // 1,048,576
  unsigned short* w   = (unsigned short*)d_ws;
  unsigned short* qb  = w; w += SA;
  unsigned short* kb  = w; w += SA;
  unsigned short* vb  = w; w += SA;
  unsigned short* wqb = w; w += SW;
  unsigned short* wkb = w; w += SW;
  unsigned short* wvb = w; w += SW;
  unsigned short* wob = w; w += SW;
  unsigned short* qh  = w; w += SA;   // (B,H,L,DH) roped
  unsigned short* kh  = w; w += SA;   // (B,H,L,DH) roped
  unsigned short* vt  = w; w += SA;   // (B,H,DH,L)
  unsigned short* Ob  = w; w += SA;   // (B,L,H*DH)

  CastArgs ca;
  ca.src[0] = q;  ca.dst[0] = qb;
  ca.src[1] = k;  ca.dst[1] = kb;
  ca.src[2] = v;  ca.dst[2] = vb;
  ca.src[3] = wq; ca.dst[3] = wqb;
  ca.src[4] = wk; ca.dst[4] = wkb;
  ca.src[5] = wv; ca.dst[5] = wvb;
  ca.src[6] = wo; ca.dst[6] = wob;
  cast_bf16_kernel<<<dim3(8192), 256, 0, stream>>>(ca);

  ProjArgs pa;
  pa.A[0] = qb; pa.Bt[0] = wqb; pa.C[0] = qh;
  pa.A[1] = kb; pa.Bt[1] = wkb; pa.C[1] = kh;
  pa.A[2] = vb; pa.Bt[2] = wvb; pa.C[2] = vt;
  gemm_proj_kernel<<<dim3(16 * 32 * 3), 256, 0, stream>>>(pa);

  attn_kernel<<<dim3(32 * 32), 256, 0, stream>>>(qh, kh, vt, Ob);
  gemm_out_kernel<<<dim3(16 * 32), 256, 0, stream>>>(Ob, wob, (float*)d_out);
}

// Round 12
// 177.837 us; speedup vs baseline: 1.0659x; 1.0124x over previous
//
#include <hip/hip_runtime.h>
#include <stdint.h>

// Problem constants (B, L, DIM) = (2, 2048, 1024); H=16, DH=64, W=256.
#define B_    2
#define L_    2048
#define DIM_  1024
#define H_    16
#define DH_   64
#define WWIN  256

typedef __attribute__((ext_vector_type(4))) float f32x4;
typedef __attribute__((ext_vector_type(8))) short bf16x8;

__device__ __forceinline__ unsigned short f2bf(float x) {
  union { float f; unsigned u; } c; c.f = x;
  unsigned r = c.u + 0x7fffu + ((c.u >> 16) & 1u);   // RNE
  return (unsigned short)(r >> 16);
}

// ---------------------------------------------------------------- cast fp32->bf16
// 8 elems/thread (two float4 loads, one 16B store). Exact flat grid:
// 3 activation arrays x 2048 blocks + 4 weight arrays x 512 = 8192 blocks.
struct CastArgs {
  const float* src[7];
  unsigned short* dst[7];
};
__global__ __launch_bounds__(256) void cast_bf16_kernel(CastArgs a) {
  int bid = blockIdx.x;
  int arr, base;
  if (bid < 6144) {             // activations: SA/2048 = 2048 blocks each
    arr = bid >> 11;
    base = (bid & 2047) << 11;
  } else {                      // weights: SW/2048 = 512 blocks each
    int t = bid - 6144;
    arr = 3 + (t >> 9);
    base = (t & 511) << 11;
  }
  int i = base + (int)threadIdx.x * 8;
  float4 v0 = *(const float4*)(a.src[arr] + i);
  float4 v1 = *(const float4*)(a.src[arr] + i + 4);
  union { ushort4 s[2]; uint4 u; } o;
  o.s[0].x = f2bf(v0.x); o.s[0].y = f2bf(v0.y); o.s[0].z = f2bf(v0.z); o.s[0].w = f2bf(v0.w);
  o.s[1].x = f2bf(v1.x); o.s[1].y = f2bf(v1.y); o.s[1].z = f2bf(v1.z); o.s[1].w = f2bf(v1.w);
  *(uint4*)(a.dst[arr] + i) = o.u;
}

// ---------------------------------------------------------------- GEMM C = A @ B^T
// Proven core (R0/R8): tile 128x64 (BM x BN), BK=64; single-barrier ping-pong
// LDS double buffer (48 KB) -> high occupancy.
#define BM 128
#define BN 64
#define BK 64

__device__ __forceinline__ void gld_lds16(const void* g, void* l) {
  __builtin_amdgcn_global_load_lds(
      (const __attribute__((address_space(1))) void*)g,
      (__attribute__((address_space(3))) void*)l, 16, 0, 0);
}

// As: 2 x 8192 shorts, Bs: 2 x 4096 shorts (ping-pong).
__device__ __forceinline__ void gemm_core_1024(
    const unsigned short* __restrict__ A, const unsigned short* __restrict__ Bt,
    unsigned short* As, unsigned short* Bs, f32x4 (&acc)[2][4],
    int m0, int n0) {
  const int tid = threadIdx.x;
  const int wave = tid >> 6, lane = tid & 63;
  const int quad = lane >> 4, l16 = lane & 15;
  const int srow = tid >> 3, sc = tid & 7;

  auto stage = [&](int k0, int buf) {
    unsigned short* Ad = As + buf * 8192;
    unsigned short* Bd = Bs + buf * 4096;
    #pragma unroll
    for (int rd = 0; rd < 4; ++rd) {       // A: 128 rows x 8 chunks
      int row = rd * 32 + srow;
      int cs = sc ^ (row & 7);             // swizzled global chunk -> linear LDS slot
      gld_lds16(A + (size_t)(m0 + row) * 1024 + k0 + cs * 8, Ad + row * BK + sc * 8);
    }
    #pragma unroll
    for (int rd = 0; rd < 2; ++rd) {       // B: 64 rows x 8 chunks
      int row = rd * 32 + srow;
      int cs = sc ^ (row & 7);
      gld_lds16(Bt + (size_t)(n0 + row) * 1024 + k0 + cs * 8, Bd + row * BK + sc * 8);
    }
  };

  stage(0, 0);
  for (int k = 0; k < 16; ++k) {
    const int cur = k & 1;
    __syncthreads();                       // drains vmcnt -> buf[cur] ready; also
                                           // orders last iter's readers of buf[cur^1]
    if (k < 15) stage((k + 1) * BK, cur ^ 1);
    const unsigned short* Ac = As + cur * 8192;
    const unsigned short* Bc = Bs + cur * 4096;
    #pragma unroll
    for (int ks = 0; ks < 2; ++ks) {
      bf16x8 af[2], bfr[4];
      #pragma unroll
      for (int i = 0; i < 2; ++i) {
        int row = wave * 32 + i * 16 + l16;
        int ch = (ks * 4 + quad) ^ (row & 7);
        af[i] = *(const bf16x8*)(Ac + row * BK + ch * 8);
      }
      #pragma unroll
      for (int j = 0; j < 4; ++j) {
        int row = j * 16 + l16;
        int ch = (ks * 4 + quad) ^ (row & 7);
        bfr[j] = *(const bf16x8*)(Bc + row * BK + ch * 8);
      }
      #pragma unroll
      for (int i = 0; i < 2; ++i)
        #pragma unroll
        for (int j = 0; j < 4; ++j)
          acc[i][j] = __builtin_amdgcn_mfma_f32_16x16x32_bf16(af[i], bfr[j], acc[i][j], 0, 0, 0);
    }
  }
}

// Projection GEMM with fused epilogues (RoPE for q/k, V-transpose for v).
// Flat grid of 1536; XCD-aware decode: each XCD gets 12 (m,z)-groups x 16 n.
struct ProjArgs {
  const unsigned short* A[3];
  const unsigned short* Bt[3];
  unsigned short* C[3];
};
__global__ __launch_bounds__(256) void gemm_proj_kernel(ProjArgs pa) {
  __shared__ unsigned short SH[24576];   // As dbuf (16384) + Bs dbuf (8192) = 48 KB
  unsigned short* As = SH;
  unsigned short* Bs = SH + 16384;

  const int bflat = blockIdx.x;
  const int xcd = bflat & 7, s = bflat >> 3;      // s: 0..191
  const int nblk = s & 15;                        // n strip (also the head h)
  const int mz = xcd * 12 + (s >> 4);             // 0..95
  const int z = mz >> 5;                          // input select
  const int mblk = mz & 31;
  const int m0 = mblk * BM, n0 = nblk * BN;

  f32x4 acc[2][4] = {};
  gemm_core_1024(pa.A[z], pa.Bt[z], As, Bs, acc, m0, n0);

  const int tid = threadIdx.x;
  const int lane = tid & 63, wave = tid >> 6;
  const int quad = lane >> 4, l16 = lane & 15;

  if (z < 2) {
    // -------- RoPE + scatter to (B,H,L,DH); h = nblk is block-uniform --------
    float frev[4];
    #pragma unroll
    for (int j = 0; j < 4; ++j) {
      int d = j * 16 + l16;
      frev[j] = exp2f(-(float)(d >> 1) * 0.41524101186092029f) * 0.15915494309189535f;
    }
    unsigned short* C = pa.C[z];
    const int h = nblk;
    const bool even = (l16 & 1) == 0;
    #pragma unroll
    for (int i = 0; i < 2; ++i)
      #pragma unroll
      for (int r = 0; r < 4; ++r) {
        int m = m0 + wave * 32 + i * 16 + quad * 4 + r;
        int b = m >> 11, l = m & (L_ - 1);
        float lf = (float)l;
        #pragma unroll
        for (int j = 0; j < 4; ++j) {
          int d = j * 16 + l16;
          float v = acc[i][j][r];
          float p = __shfl_xor(v, 1);       // partner at d^1
          float a = lf * frev[j];
          float t = a - floorf(a);          // revolutions in [0,1)
          float sn = __builtin_amdgcn_sinf(t);
          float cs = __builtin_amdgcn_cosf(t);
          float o = even ? (v * cs - p * sn) : (p * sn + v * cs);
          C[(((size_t)b * H_ + h) * L_ + l) * DH_ + d] = f2bf(o);
        }
      }
  } else {
    // -------- V: per-wave 64(n) x 32(m) transpose via LDS, store (B,H,DH,L) --------
    __syncthreads();   // T overlaps dbuf regions other waves may still be reading
    unsigned short* T = SH + wave * 2304;   // 64 rows x 36 shorts (pad: 72B stride)
    #pragma unroll
    for (int i = 0; i < 2; ++i)
      #pragma unroll
      for (int j = 0; j < 4; ++j) {
        int nw = j * 16 + l16;
        int hm = i * 4 + quad;                      // 4-short group in m (0..7)
        uint2 pk;
        pk.x = (unsigned)f2bf(acc[i][j][0]) | ((unsigned)f2bf(acc[i][j][1]) << 16);
        pk.y = (unsigned)f2bf(acc[i][j][2]) | ((unsigned)f2bf(acc[i][j][3]) << 16);
        *(uint2*)(T + nw * 36 + hm * 4) = pk;       // ds_write_b64
      }
    asm volatile("s_waitcnt lgkmcnt(0)" ::: "memory");  // wave-private: no barrier
    int h = nblk;                                   // BN=64: one head per block
    int d = lane;
    int b = m0 >> 11;
    int lbase = (m0 & (L_ - 1)) + wave * 32;
    unsigned short* C = pa.C[2];
    size_t rowbase = (((size_t)b * H_ + h) * DH_ + d) * L_ + lbase;
    #pragma unroll
    for (int t = 0; t < 4; ++t) {
      uint2 lo = *(uint2*)(T + lane * 36 + t * 8);
      uint2 hi = *(uint2*)(T + lane * 36 + t * 8 + 4);
      uint4 o = {lo.x, lo.y, hi.x, hi.y};           // m-local [8t, 8t+8)
      *(uint4*)(C + rowbase + t * 8) = o;
    }
  }
}

// Output GEMM: fp32 row-major epilogue straight to d_out.
// Flat grid of 512; XCD-aware decode: each XCD gets 4 m-groups x 16 n.
__global__ __launch_bounds__(256) void gemm_out_kernel(
    const unsigned short* __restrict__ A, const unsigned short* __restrict__ Bt,
    float* __restrict__ C) {
  __shared__ unsigned short SH[24576];
  unsigned short* As = SH;
  unsigned short* Bs = SH + 16384;

  const int bflat = blockIdx.x;
  const int xcd = bflat & 7, s = bflat >> 3;      // s: 0..63
  const int nblk = s & 15;
  const int mblk = xcd * 4 + (s >> 4);            // 0..31
  const int m0 = mblk * BM, n0 = nblk * BN;

  f32x4 acc[2][4] = {};
  gemm_core_1024(A, Bt, As, Bs, acc, m0, n0);

  const int lane = threadIdx.x & 63, wave = threadIdx.x >> 6;
  const int quad = lane >> 4, l16 = lane & 15;
  #pragma unroll
  for (int i = 0; i < 2; ++i)
    #pragma unroll
    for (int j = 0; j < 4; ++j)
      #pragma unroll
      for (int r = 0; r < 4; ++r) {
        int m = m0 + wave * 32 + i * 16 + quad * 4 + r;
        int n = n0 + j * 16 + l16;
        C[(size_t)m * DIM_ + n] = acc[i][j][r];
      }
}

// ---------------------------------------------------------------- attention
// R19: R18 structure, but V staging is issued AFTER the QK^T loop. vmcnt
// retires in-order (m135): with V issued first, every K-fragment wait had to
// drain all 10 V gld_lds before QK could start. Issuing K first lets QK run
// immediately; V latency hides under the softmax VALU phase; the pre-PV
// __syncthreads (vmcnt(0) drain) still guarantees V readiness.
#define VSTR 320
__global__ __launch_bounds__(256, 4) void attn_kernel(
    const unsigned short* __restrict__ Qh,  // (B,H,L,DH) roped
    const unsigned short* __restrict__ Kh,  // (B,H,L,DH) roped
    const unsigned short* __restrict__ Vt,  // (B,H,DH,L)
    unsigned short* __restrict__ O) {       // (B,L,H*DH) bf16
  __shared__ unsigned short Vs[64 * VSTR];  // 40960 B exactly -> 4 blocks/CU
  const int tid = threadIdx.x;
  const int wave = tid >> 6, lane = tid & 63;
  const int quad = lane >> 4, l16 = lane & 15;

  const int bflat = blockIdx.x;
  const int xcd = bflat & 7, s = bflat >> 3;  // s: 0..127
  const int qt = s >> 2;                      // 0..31 q-tile (64 queries)
  const int bh = xcd * 4 + (s & 3);           // 0..31

  const int q0 = qt * 64;
  const int qb = q0 + wave * 16;              // this wave's 16 queries
  const int kw0 = qb - WWIN;                  // per-wave window start
  const bool edge = (kw0 < 0);

  // ---- Q fragments (B-operand: lane l16 = q-col, quad*8+j = d) ----
  bf16x8 qf0, qf1;
  {
    const unsigned short* qrow = Qh + ((size_t)bh * L_ + qb + l16) * DH_;
    qf0 = *(const bf16x8*)(qrow + quad * 8);
    qf1 = *(const bf16x8*)(qrow + 32 + quad * 8);
  }

  // ---- S^T = K Q^T: 17 static chunks, K direct from global ----
  // D layout: col=l16 = q, row=quad*4+r = key-within-chunk.
  f32x4 S[17] = {};
  const unsigned short* kbase = Kh + (size_t)bh * L_ * DH_;
  __builtin_amdgcn_s_setprio(1);
  #pragma unroll
  for (int c = 0; c < 17; ++c) {
    int key = kw0 + c * 16 + l16;
    key = key < 0 ? 0 : key;                // clamp: finite garbage, masked pre-exp
    const unsigned short* kr = kbase + (size_t)key * DH_ + quad * 8;
    bf16x8 kf0 = *(const bf16x8*)(kr);
    bf16x8 kf1 = *(const bf16x8*)(kr + 32);
    S[c] = __builtin_amdgcn_mfma_f32_16x16x32_bf16(kf0, qf0, S[c], 0, 0, 0);
    S[c] = __builtin_amdgcn_mfma_f32_16x16x32_bf16(kf1, qf1, S[c], 0, 0, 0);
  }
  __builtin_amdgcn_s_setprio(0);

  // ---- stage V via global_load_lds (issued AFTER QK loads; completes under
  // softmax). 64 d-rows x 40 chunks, keys [q0-256, q0+63]; source chunk
  // pre-swizzled: LDS slot ch holds global chunk ch^(row&7).
  const unsigned short* vbase = Vt + (size_t)bh * DH_ * L_;
  #pragma unroll
  for (int it = 0; it < 10; ++it) {         // 2560 = 64*40 chunks, exact
    int ci = it * 256 + tid;
    int row = ci / 40, ch = ci - row * 40;
    int gch = ch ^ (row & 7);               // stays in [0,40): 8-aligned blocks
    int key0 = q0 - WWIN + gch * 8;
    key0 = key0 < 0 ? 0 : key0;             // edge tiles: finite data, P=0 there
    gld_lds16(vbase + (size_t)row * L_ + key0, Vs + ci * 8);
  }

  // ---- masks (lane q = l16; key offset off16 = quad*4 + r) ----
  const int off16 = quad * 4;
  #pragma unroll
  for (int r = 0; r < 4; ++r) {
    if (off16 + r < l16)  S[0][r]  = -1e30f;   // window lower bound
    if (off16 + r > l16)  S[16][r] = -1e30f;   // causal upper bound
  }
  if (edge) {
    #pragma unroll
    for (int c = 0; c < 17; ++c)
      #pragma unroll
      for (int r = 0; r < 4; ++r)
        if (kw0 + c * 16 + off16 + r < 0) S[c][r] = -1e30f;
  }

  // ---- softmax: reduce over (c, r) in-lane, then across quads ----
  float mx = -1e30f;
  #pragma unroll
  for (int c = 0; c < 17; ++c)
    #pragma unroll
    for (int r = 0; r < 4; ++r)
      mx = fmaxf(mx, S[c][r]);
  mx = fmaxf(mx, __shfl_xor(mx, 16));
  mx = fmaxf(mx, __shfl_xor(mx, 32));
  float sum = 0.f;
  #pragma unroll
  for (int c = 0; c < 17; ++c)
    #pragma unroll
    for (int r = 0; r < 4; ++r) {
      // exp(0.125*(S-mx)) = exp2((S-mx) * 0.125*log2(e))
      float e = __builtin_amdgcn_exp2f((S[c][r] - mx) * 0.18033688011112042f);
      S[c][r] = e;
      sum += e;
    }
  sum += __shfl_xor(sum, 16);
  sum += __shfl_xor(sum, 32);
  const float ivl = 1.0f / sum;

  __syncthreads();                          // drains vmcnt: all V staged

  // ---- O = P V: build A-fragment in registers, V from LDS ----
  // Lane (l16,quad) needs P[q=l16][key=32g+8*quad+j]; source regs live at
  // quads 2*(quad&1), 2*(quad&1)+1 with chunk c' = 2g + (quad>>1).
  f32x4 Oacc[4] = {};
  const int srcA = (lane & 15) | ((lane & 16) << 1);   // quad 0 or 2
  const int srcB = srcA + 16;                          // quad 1 or 3
  const bool loq = quad < 2;
  #pragma unroll
  for (int g = 0; g < 9; ++g) {
    unsigned uA0, uA1, uB0, uB1;
    {
      float a0 = S[2 * g][0] * ivl, a1 = S[2 * g][1] * ivl;
      float a2 = S[2 * g][2] * ivl, a3 = S[2 * g][3] * ivl;
      asm("v_cvt_pk_bf16_f32 %0, %1, %2" : "=v"(uA0) : "v"(a0), "v"(a1));
      asm("v_cvt_pk_bf16_f32 %0, %1, %2" : "=v"(uA1) : "v"(a2), "v"(a3));
    }
    if (g < 8) {
      float b0 = S[2 * g + 1][0] * ivl, b1 = S[2 * g + 1][1] * ivl;
      float b2 = S[2 * g + 1][2] * ivl, b3 = S[2 * g + 1][3] * ivl;
      asm("v_cvt_pk_bf16_f32 %0, %1, %2" : "=v"(uB0) : "v"(b0), "v"(b1));
      asm("v_cvt_pk_bf16_f32 %0, %1, %2" : "=v"(uB1) : "v"(b2), "v"(b3));
    } else {
      uB0 = 0; uB1 = 0;                     // tail keys: P = 0
    }
    unsigned tA0a = __shfl(uA0, srcA), tA1a = __shfl(uA1, srcA);
    unsigned tB0a = __shfl(uB0, srcA), tB1a = __shfl(uB1, srcA);
    unsigned tA0b = __shfl(uA0, srcB), tA1b = __shfl(uA1, srcB);
    unsigned tB0b = __shfl(uB0, srcB), tB1b = __shfl(uB1, srcB);
    union { unsigned u[4]; bf16x8 v; } pav;
    pav.u[0] = loq ? tA0a : tB0a;
    pav.u[1] = loq ? tA1a : tB1a;
    pav.u[2] = loq ? tA0b : tB0b;
    pav.u[3] = loq ? tA1b : tB1b;
    // V read: global chunk C -> LDS slot C^(row&7); zero-P tail clamps in-range
    int C = wave * 2 + g * 4 + quad;
    if (g == 8) C = C > 39 ? 39 : C;        // only quads>=2 (P=0) can exceed
    __builtin_amdgcn_s_setprio(1);
    #pragma unroll
    for (int t = 0; t < 4; ++t) {
      int row = t * 16 + l16;
      int slot = C ^ (row & 7);
      bf16x8 vf = *(const bf16x8*)(&Vs[row * VSTR + slot * 8]);
      Oacc[t] = __builtin_amdgcn_mfma_f32_16x16x32_bf16(pav.v, vf, Oacc[t], 0, 0, 0);
    }
    __builtin_amdgcn_s_setprio(0);
  }

  // epilogue: (B, L, H*DH) bf16; D: row=quad*4+r = q, col=l16 (+16t) = d
  int b = bh >> 4, h = bh & 15;
  #pragma unroll
  for (int t = 0; t < 4; ++t)
    #pragma unroll
    for (int r = 0; r < 4; ++r) {
      int l = qb + quad * 4 + r;
      int col = h * DH_ + t * 16 + l16;
      O[((size_t)b * L_ + l) * (H_ * DH_) + col] = f2bf(Oacc[t][r]);
    }
}

// ---------------------------------------------------------------- launch
extern "C" void kernel_launch(void* const* d_in, const int* in_sizes, int n_in,
                              void* d_out, int out_size, void* d_ws, size_t ws_size,
                              hipStream_t stream) {
  const float* q  = (const float*)d_in[0];
  const float* k  = (const float*)d_in[1];
  const float* v  = (const float*)d_in[2];
  const float* wq = (const float*)d_in[3];
  const float* wk = (const float*)d_in[4];
  const float* wv = (const float*)d_in[5];
  const float* wo = (const float*)d_in[6];

  const size_t SA = (size_t)B_ * L_ * DIM_;  // 4,194,304
  const size_t SW = (size_t)DIM_ * DIM_;     // 1,048,576
  unsigned short* w   = (unsigned short*)d_ws;
  unsigned short* qb  = w; w += SA;
  unsigned short* kb  = w; w += SA;
  unsigned short* vb  = w; w += SA;
  unsigned short* wqb = w; w += SW;
  unsigned short* wkb = w; w += SW;
  unsigned short* wvb = w; w += SW;
  unsigned short* wob = w; w += SW;
  unsigned short* qh  = w; w += SA;   // (B,H,L,DH) roped
  unsigned short* kh  = w; w += SA;   // (B,H,L,DH) roped
  unsigned short* vt  = w; w += SA;   // (B,H,DH,L)
  unsigned short* Ob  = w; w += SA;   // (B,L,H*DH)

  CastArgs ca;
  ca.src[0] = q;  ca.dst[0] = qb;
  ca.src[1] = k;  ca.dst[1] = kb;
  ca.src[2] = v;  ca.dst[2] = vb;
  ca.src[3] = wq; ca.dst[3] = wqb;
  ca.src[4] = wk; ca.dst[4] = wkb;
  ca.src[5] = wv; ca.dst[5] = wvb;
  ca.src[6] = wo; ca.dst[6] = wob;
  cast_bf16_kernel<<<dim3(8192), 256, 0, stream>>>(ca);

  ProjArgs pa;
  pa.A[0] = qb; pa.Bt[0] = wqb; pa.C[0] = qh;
  pa.A[1] = kb; pa.Bt[1] = wkb; pa.C[1] = kh;
  pa.A[2] = vb; pa.Bt[2] = wvb; pa.C[2] = vt;
  gemm_proj_kernel<<<dim3(16 * 32 * 3), 256, 0, stream>>>(pa);

  attn_kernel<<<dim3(32 * 32), 256, 0, stream>>>(qh, kh, vt, Ob);
  gemm_out_kernel<<<dim3(16 * 32), 256, 0, stream>>>(Ob, wob, (float*)d_out);
}